// Round 1
// baseline (83.817 us; speedup 1.0000x reference)
//
#include <hip/hip_runtime.h>

// B=4, S=256, P=64, D=63  -> 1024 slices, one block per slice.
// inputs : [1024][64][64] fp32  (last col = conf)
// targets: [1024][64][63] fp32
// out    : [1024] fp32

__global__ __launch_bounds__(256, 4) void chamfer_kernel(
    const float* __restrict__ inputs,
    const float* __restrict__ targets,
    float* __restrict__ out)
{
    __shared__ float pT[63 * 64];      // pT[d*64 + i] = pred[i][d]
    __shared__ float tT[63 * 64];      // tT[d*64 + j] = targ[j][d]
    __shared__ float conf_s[64];
    __shared__ float rconf_s[64];
    __shared__ float pn_s[64];         // ||p_i||^2
    __shared__ float tn_s[64];         // ||t_j||^2
    __shared__ float colpart[16 * 64]; // per-ti partial col mins
    __shared__ float t1part[16];       // per-ti partial term1

    const int tid = threadIdx.x;
    const int bid = blockIdx.x;

    // ---- stage 1: load inputs slice (64x64 floats) transposed into LDS ----
    {
        const float* src = inputs + (size_t)bid * 4096 + (size_t)tid * 16;
        const int i  = tid >> 2;          // row (pred index)
        const int db = (tid & 3) * 16;    // starting d of this thread's chunk
        #pragma unroll
        for (int k = 0; k < 4; ++k) {
            float4 v = *(const float4*)(src + k * 4);
            float vv[4] = {v.x, v.y, v.z, v.w};
            #pragma unroll
            for (int c = 0; c < 4; ++c) {
                int d = db + k * 4 + c;
                if (d < 63) {
                    pT[d * 64 + i] = vv[c];
                } else {
                    conf_s[i]  = vv[c];
                    rconf_s[i] = 1.0f / vv[c];
                }
            }
        }
    }
    // ---- targets slice (64x63 = 4032 floats), 252 threads x 16 floats ----
    if (tid < 252) {
        const float* src = targets + (size_t)bid * 4032 + (size_t)tid * 16;
        #pragma unroll
        for (int k = 0; k < 4; ++k) {
            float4 v = *(const float4*)(src + k * 4);
            float vv[4] = {v.x, v.y, v.z, v.w};
            #pragma unroll
            for (int c = 0; c < 4; ++c) {
                unsigned e = (unsigned)tid * 16u + (unsigned)k * 4u + (unsigned)c;
                unsigned i = e / 63u;
                unsigned d = e - i * 63u;
                tT[d * 64 + i] = vv[c];
            }
        }
    }
    __syncthreads();

    // ---- stage 1b: squared norms ----
    if (tid < 64) {
        float s = 0.0f;
        #pragma unroll 7
        for (int d = 0; d < 63; ++d) { float x = pT[d * 64 + tid]; s = fmaf(x, x, s); }
        pn_s[tid] = s;
    } else if (tid < 128) {
        const int i = tid - 64;
        float s = 0.0f;
        #pragma unroll 7
        for (int d = 0; d < 63; ++d) { float x = tT[d * 64 + i]; s = fmaf(x, x, s); }
        tn_s[i] = s;
    }
    __syncthreads();

    // ---- stage 2: 4x4 register tile of dot products ----
    const int ti = tid >> 4;   // 0..15 -> rows ti*4 .. ti*4+3
    const int tj = tid & 15;   // 0..15 -> cols tj*4 .. tj*4+3
    float acc[4][4] = {};
    #pragma unroll 7
    for (int d = 0; d < 63; ++d) {
        float4 p = *(const float4*)&pT[d * 64 + ti * 4];
        float4 t = *(const float4*)&tT[d * 64 + tj * 4];
        float pa[4] = {p.x, p.y, p.z, p.w};
        float ta[4] = {t.x, t.y, t.z, t.w};
        #pragma unroll
        for (int ii = 0; ii < 4; ++ii)
            #pragma unroll
            for (int jj = 0; jj < 4; ++jj)
                acc[ii][jj] = fmaf(pa[ii], ta[jj], acc[ii][jj]);
    }

    // ---- stage 3: distances + reductions ----
    float pnv[4], cf[4], rc[4], tnv[4];
    #pragma unroll
    for (int ii = 0; ii < 4; ++ii) {
        pnv[ii] = pn_s[ti * 4 + ii];
        cf[ii]  = conf_s[ti * 4 + ii];
        rc[ii]  = rconf_s[ti * 4 + ii];
    }
    #pragma unroll
    for (int jj = 0; jj < 4; ++jj) tnv[jj] = tn_s[tj * 4 + jj];

    float rowmin[4] = {1e30f, 1e30f, 1e30f, 1e30f};
    float colmin[4] = {1e30f, 1e30f, 1e30f, 1e30f};
    #pragma unroll
    for (int ii = 0; ii < 4; ++ii) {
        #pragma unroll
        for (int jj = 0; jj < 4; ++jj) {
            float d2   = pnv[ii] + tnv[jj] - 2.0f * acc[ii][jj];
            float dist = sqrtf(fmaxf(d2, 0.0f));
            rowmin[ii] = fminf(rowmin[ii], dist);
            colmin[jj] = fminf(colmin[jj], dist * rc[ii]);
        }
    }

    // row-min across tj group (lanes differing in bits 0..3)
    #pragma unroll
    for (int m = 1; m <= 8; m <<= 1) {
        #pragma unroll
        for (int ii = 0; ii < 4; ++ii)
            rowmin[ii] = fminf(rowmin[ii], __shfl_xor(rowmin[ii], m, 64));
    }
    if (tj == 0) {
        float s = 0.0f;
        #pragma unroll
        for (int ii = 0; ii < 4; ++ii) s = fmaf(cf[ii], rowmin[ii], s);
        t1part[ti] = s;
    }
    #pragma unroll
    for (int jj = 0; jj < 4; ++jj) colpart[ti * 64 + tj * 4 + jj] = colmin[jj];
    __syncthreads();

    // ---- final reduce: wave 0 only ----
    if (tid < 64) {
        float m = colpart[tid];
        #pragma unroll
        for (int t = 1; t < 16; ++t) m = fminf(m, colpart[t * 64 + tid]);
        float v = m + (tid < 16 ? t1part[tid] : 0.0f);
        #pragma unroll
        for (int msk = 1; msk <= 32; msk <<= 1)
            v += __shfl_xor(v, msk, 64);
        if (tid == 0) out[bid] = v;
    }
}

extern "C" void kernel_launch(void* const* d_in, const int* in_sizes, int n_in,
                              void* d_out, int out_size, void* d_ws, size_t ws_size,
                              hipStream_t stream) {
    const float* inputs  = (const float*)d_in[0];
    const float* targets = (const float*)d_in[1];
    float* out = (float*)d_out;
    hipLaunchKernelGGL(chamfer_kernel, dim3(1024), dim3(256), 0, stream,
                       inputs, targets, out);
}

// Round 4
// 75.400 us; speedup vs baseline: 1.1116x; 1.1116x over previous
//
#include <hip/hip_runtime.h>

// B=4, S=256, P=64, D=63 -> 1024 slices, one block per slice, 4 waves.
// dist^2[i][j] = ||p_i||^2 + ||t_j||^2 - 2 * (p_i . t_j)
// dot matrix via mfma_f32_16x16x32_bf16 (K=63 padded to 64 -> 2 MFMAs per 16x16 tile).
// Norms computed from the SAME bf16-rounded values (self-consistent, d2 >= -eps).

typedef __attribute__((ext_vector_type(8))) short s16x8;
typedef __attribute__((ext_vector_type(8))) unsigned short u16x8;
typedef __attribute__((ext_vector_type(4))) float f32x4;

__device__ __forceinline__ unsigned short f2bf(float x) {
    unsigned u = __float_as_uint(x);
    u += 0x7FFFu + ((u >> 16) & 1u);          // round-to-nearest-even
    return (unsigned short)(u >> 16);
}
__device__ __forceinline__ float bf2f(unsigned short h) {
    return __uint_as_float(((unsigned)h) << 16);
}
// XOR-swizzled ushort index of the 8-element chunk (row-major [64][64] bf16, 128B rows)
__device__ __forceinline__ int swz(int row, int chunk) {
    return row * 64 + ((chunk ^ (row & 7)) << 3);
}

__global__ __launch_bounds__(256, 4) void chamfer_mfma(
    const float* __restrict__ inputs,
    const float* __restrict__ targets,
    float* __restrict__ out)
{
    __shared__ unsigned short pA[64 * 64];   // bf16 preds, swizzled
    __shared__ unsigned short tB[64 * 64];   // bf16 targets, swizzled
    __shared__ float conf_s[64], rc2_s[64], pn_s[64], tn_s[64];
    __shared__ float colpart[4][64];
    __shared__ float t1part[4];

    const int tid = threadIdx.x;
    const int bid = blockIdx.x;

    // ---- stage inputs slice (64 rows x 64 floats; col 63 = conf) ----
    {
        const int i  = tid >> 2;
        const int cb = (tid & 3) * 16;
        const float* src = inputs + (size_t)bid * 4096 + i * 64 + cb;
        float vals[16];
        #pragma unroll
        for (int k = 0; k < 4; ++k) {
            float4 v = *(const float4*)(src + k * 4);
            vals[k*4+0] = v.x; vals[k*4+1] = v.y; vals[k*4+2] = v.z; vals[k*4+3] = v.w;
        }
        unsigned short h[16];
        float s = 0.f;
        #pragma unroll
        for (int k = 0; k < 16; ++k) {
            int d = cb + k;
            if (d < 63) {
                h[k] = f2bf(vals[k]);
                float xb = bf2f(h[k]);
                s = fmaf(xb, xb, s);
            } else {                       // d == 63: confidence column
                h[k] = 0;
                conf_s[i] = vals[k];
                float r = 1.0f / vals[k];
                rc2_s[i] = r * r;
            }
        }
        // reduce ||p_i||^2 across the 4 threads of this row (consecutive lanes)
        s += __shfl_xor(s, 1, 64);
        s += __shfl_xor(s, 2, 64);
        if ((tid & 3) == 0) pn_s[i] = s;
        u16x8 c0, c1;
        #pragma unroll
        for (int k = 0; k < 8; ++k) { c0[k] = h[k]; c1[k] = h[8 + k]; }
        const int cbase = (tid & 3) * 2;
        *(u16x8*)&pA[swz(i, cbase)]     = c0;
        *(u16x8*)&pA[swz(i, cbase + 1)] = c1;
    }
    // zero-pad tB column 63
    if (tid < 64) tB[swz(tid, 7) + 7] = 0;
    // ---- stage targets slice (64 x 63 floats = 4032) ----
    if (tid < 252) {
        const float* src = targets + (size_t)bid * 4032 + tid * 16;
        #pragma unroll
        for (int k = 0; k < 4; ++k) {
            float4 v = *(const float4*)(src + k * 4);
            float vv[4] = {v.x, v.y, v.z, v.w};
            #pragma unroll
            for (int c = 0; c < 4; ++c) {
                int e = tid * 16 + k * 4 + c;
                int i = e / 63;
                int d = e - i * 63;
                tB[swz(i, d >> 3) + (d & 7)] = f2bf(vv[c]);
            }
        }
    }
    __syncthreads();

    // ---- ||t_j||^2 from staged bf16 (wave 1 while others start MFMA) ----
    if (tid >= 64 && tid < 128) {
        const int j = tid - 64;
        float s = 0.f;
        #pragma unroll
        for (int c = 0; c < 8; ++c) {
            u16x8 v = *(const u16x8*)&tB[swz(j, c)];
            #pragma unroll
            for (int k = 0; k < 8; ++k) { float x = bf2f(v[k]); s = fmaf(x, x, s); }
        }
        tn_s[j] = s;
    }

    // ---- MFMA: wave w owns rows w*16..w*16+15, all 64 cols ----
    const int w  = tid >> 6, l = tid & 63;
    const int lr = l & 15, lg = l >> 4;      // A: row=lr, k=lg*8+i ; B: col=lr, k=lg*8+i
    s16x8 a0 = *(const s16x8*)&pA[swz(w * 16 + lr, 0 + lg)];
    s16x8 a1 = *(const s16x8*)&pA[swz(w * 16 + lr, 4 + lg)];
    f32x4 acc[4];
    #pragma unroll
    for (int ct = 0; ct < 4; ++ct) {
        const int n = ct * 16 + lr;
        s16x8 b0 = *(const s16x8*)&tB[swz(n, 0 + lg)];
        s16x8 b1 = *(const s16x8*)&tB[swz(n, 4 + lg)];
        f32x4 c = {0.f, 0.f, 0.f, 0.f};
        c = __builtin_amdgcn_mfma_f32_16x16x32_bf16(a0, b0, c, 0, 0, 0);
        c = __builtin_amdgcn_mfma_f32_16x16x32_bf16(a1, b1, c, 0, 0, 0);
        acc[ct] = c;
    }
    __syncthreads();   // tn_s ready

    // ---- epilogue: C/D map col=lane&15, row=(lane>>4)*4+reg (m89-verified) ----
    const int r0 = w * 16 + lg * 4;
    float pn4[4], cf4[4], rc4[4], tn4[4];
    #pragma unroll
    for (int q = 0; q < 4; ++q) {
        pn4[q] = pn_s[r0 + q];
        cf4[q] = conf_s[r0 + q];
        rc4[q] = rc2_s[r0 + q];
    }
    #pragma unroll
    for (int ct = 0; ct < 4; ++ct) tn4[ct] = tn_s[ct * 16 + lr];

    float rowmin[4]  = {1e30f, 1e30f, 1e30f, 1e30f};   // min over cols of d2
    float colminl[4] = {1e30f, 1e30f, 1e30f, 1e30f};   // min over rows of d2*rconf^2
    #pragma unroll
    for (int ct = 0; ct < 4; ++ct) {
        #pragma unroll
        for (int q = 0; q < 4; ++q) {
            float d2 = fmaf(-2.f, acc[ct][q], pn4[q] + tn4[ct]);
            rowmin[q]   = fminf(rowmin[q], d2);
            colminl[ct] = fminf(colminl[ct], d2 * rc4[q]);
        }
    }
    // row-min across the 16 col-lanes (bits 0..3)
    #pragma unroll
    for (int m = 1; m <= 8; m <<= 1) {
        #pragma unroll
        for (int q = 0; q < 4; ++q)
            rowmin[q] = fminf(rowmin[q], __shfl_xor(rowmin[q], m, 64));
    }
    float s = 0.f;
    if (lr == 0) {
        #pragma unroll
        for (int q = 0; q < 4; ++q) s = fmaf(cf4[q], sqrtf(fmaxf(rowmin[q], 0.f)), s);
    }
    s += __shfl_xor(s, 16, 64);
    s += __shfl_xor(s, 32, 64);
    if (l == 0) t1part[w] = s;
    // col-min across the 4 row-groups (bits 4..5)
    #pragma unroll
    for (int m = 16; m <= 32; m <<= 1) {
        #pragma unroll
        for (int ct = 0; ct < 4; ++ct)
            colminl[ct] = fminf(colminl[ct], __shfl_xor(colminl[ct], m, 64));
    }
    if (l < 16) {
        #pragma unroll
        for (int ct = 0; ct < 4; ++ct) colpart[w][ct * 16 + l] = colminl[ct];
    }
    __syncthreads();

    // ---- final reduce (wave 0) ----
    if (tid < 64) {
        float m0 = fminf(fminf(colpart[0][tid], colpart[1][tid]),
                         fminf(colpart[2][tid], colpart[3][tid]));
        float v = sqrtf(fmaxf(m0, 0.f));
        if (tid < 4) v += t1part[tid];
        #pragma unroll
        for (int m = 1; m <= 32; m <<= 1) v += __shfl_xor(v, m, 64);
        if (tid == 0) out[bid] = v;
    }
}

extern "C" void kernel_launch(void* const* d_in, const int* in_sizes, int n_in,
                              void* d_out, int out_size, void* d_ws, size_t ws_size,
                              hipStream_t stream) {
    const float* inputs  = (const float*)d_in[0];
    const float* targets = (const float*)d_in[1];
    float* out = (float*)d_out;
    hipLaunchKernelGGL(chamfer_mfma, dim3(1024), dim3(256), 0, stream,
                       inputs, targets, out);
}

// Round 5
// 75.111 us; speedup vs baseline: 1.1159x; 1.0038x over previous
//
#include <hip/hip_runtime.h>

// B=4, S=256, P=64, D=63 -> 1024 slices, one block per slice, 4 waves.
// dist^2[i][j] = ||p_i||^2 + ||t_j||^2 - 2*(p_i . t_j); dot via mfma_f32_16x16x32_bf16.
// Norms computed from the SAME bf16-rounded values (self-consistent, d2 >= -eps).
// v3: targets staged row-aligned (no div, no scalar ds_write_b16), tn fused into
// staging (2 shfl_xor), second barrier removed.

typedef __attribute__((ext_vector_type(8))) short s16x8;
typedef __attribute__((ext_vector_type(8))) unsigned short u16x8;
typedef __attribute__((ext_vector_type(4))) float f32x4;

__device__ __forceinline__ unsigned short f2bf(float x) {
    unsigned u = __float_as_uint(x);
    u += 0x7FFFu + ((u >> 16) & 1u);          // round-to-nearest-even
    return (unsigned short)(u >> 16);
}
__device__ __forceinline__ float bf2f(unsigned short h) {
    return __uint_as_float(((unsigned)h) << 16);
}
// XOR-swizzled ushort index of the 8-element chunk (row-major [64][64] bf16, 128B rows)
__device__ __forceinline__ int swz(int row, int chunk) {
    return row * 64 + ((chunk ^ (row & 7)) << 3);
}

__global__ __launch_bounds__(256, 4) void chamfer_mfma(
    const float* __restrict__ inputs,
    const float* __restrict__ targets,
    float* __restrict__ out)
{
    __shared__ unsigned short pA[64 * 64];   // bf16 preds, swizzled
    __shared__ unsigned short tB[64 * 64];   // bf16 targets, swizzled
    __shared__ float conf_s[64], rc2_s[64], pn_s[64], tn_s[64];
    __shared__ float colpart[4][64];
    __shared__ float t1part[4];

    const int tid = threadIdx.x;
    const int bid = blockIdx.x;
    const int row = tid >> 2;     // 0..63: row this thread stages
    const int c   = tid & 3;      // 0..3 : 16-col chunk within the row
    const int cb  = c * 16;

    // ---- stage inputs slice: row-aligned [64][64] fp32, col 63 = conf ----
    {
        const float* src = inputs + (size_t)bid * 4096 + row * 64 + cb;
        float vals[16];
        #pragma unroll
        for (int k = 0; k < 4; ++k) {
            float4 v = *(const float4*)(src + k * 4);
            vals[k*4+0] = v.x; vals[k*4+1] = v.y; vals[k*4+2] = v.z; vals[k*4+3] = v.w;
        }
        unsigned short h[16];
        float s = 0.f;
        #pragma unroll
        for (int k = 0; k < 16; ++k) {
            int d = cb + k;
            if (d < 63) {
                h[k] = f2bf(vals[k]);
                float xb = bf2f(h[k]);
                s = fmaf(xb, xb, s);
            } else {                       // d == 63: confidence column
                h[k] = 0;
                conf_s[row] = vals[k];
                float r = 1.0f / vals[k];
                rc2_s[row] = r * r;
            }
        }
        s += __shfl_xor(s, 1, 64);
        s += __shfl_xor(s, 2, 64);
        if (c == 0) pn_s[row] = s;
        u16x8 h0, h1;
        #pragma unroll
        for (int k = 0; k < 8; ++k) { h0[k] = h[k]; h1[k] = h[8 + k]; }
        *(u16x8*)&pA[swz(row, 2 * c)]     = h0;
        *(u16x8*)&pA[swz(row, 2 * c + 1)] = h1;
    }

    // ---- stage targets slice: packed [64][63] fp32, row-aligned windows ----
    {
        const float* src = targets + (size_t)bid * 4032 + row * 63 + cb;
        float vals[16];
        if (c < 3) {
            #pragma unroll
            for (int k = 0; k < 4; ++k)
                __builtin_memcpy(&vals[k * 4], src + k * 4, 16);   // align-4 dwordx4
        } else {
            #pragma unroll
            for (int k = 0; k < 3; ++k)
                __builtin_memcpy(&vals[k * 4], src + k * 4, 16);
            __builtin_memcpy(&vals[12], src + 12, 12);             // dwordx3 tail, no OOB
            vals[15] = 0.f;
        }
        unsigned short h[16];
        float s = 0.f;
        #pragma unroll
        for (int k = 0; k < 16; ++k) {
            int d = cb + k;
            unsigned short hb = (d < 63) ? f2bf(vals[k]) : (unsigned short)0;
            h[k] = hb;
            float xb = bf2f(hb);
            s = fmaf(xb, xb, s);
        }
        s += __shfl_xor(s, 1, 64);
        s += __shfl_xor(s, 2, 64);
        if (c == 0) tn_s[row] = s;
        u16x8 h0, h1;
        #pragma unroll
        for (int k = 0; k < 8; ++k) { h0[k] = h[k]; h1[k] = h[8 + k]; }
        *(u16x8*)&tB[swz(row, 2 * c)]     = h0;
        *(u16x8*)&tB[swz(row, 2 * c + 1)] = h1;
    }
    __syncthreads();   // everything (tiles + all norms/conf) ready

    // ---- MFMA: wave w owns rows w*16..w*16+15, all 64 cols ----
    const int w  = tid >> 6, l = tid & 63;
    const int lr = l & 15, lg = l >> 4;      // A: row=lr, k=lg*8+i ; B: col=lr, k=lg*8+i
    s16x8 a0 = *(const s16x8*)&pA[swz(w * 16 + lr, 0 + lg)];
    s16x8 a1 = *(const s16x8*)&pA[swz(w * 16 + lr, 4 + lg)];
    f32x4 acc[4];
    #pragma unroll
    for (int ct = 0; ct < 4; ++ct) {
        const int n = ct * 16 + lr;
        s16x8 b0 = *(const s16x8*)&tB[swz(n, 0 + lg)];
        s16x8 b1 = *(const s16x8*)&tB[swz(n, 4 + lg)];
        f32x4 cc = {0.f, 0.f, 0.f, 0.f};
        cc = __builtin_amdgcn_mfma_f32_16x16x32_bf16(a0, b0, cc, 0, 0, 0);
        cc = __builtin_amdgcn_mfma_f32_16x16x32_bf16(a1, b1, cc, 0, 0, 0);
        acc[ct] = cc;
    }

    // ---- epilogue: C/D map col=lane&15, row=(lane>>4)*4+reg (m89-verified) ----
    const int r0 = w * 16 + lg * 4;
    float pn4[4], cf4[4], rc4[4], tn4[4];
    #pragma unroll
    for (int q = 0; q < 4; ++q) {
        pn4[q] = pn_s[r0 + q];
        cf4[q] = conf_s[r0 + q];
        rc4[q] = rc2_s[r0 + q];
    }
    #pragma unroll
    for (int ct = 0; ct < 4; ++ct) tn4[ct] = tn_s[ct * 16 + lr];

    float rowmin[4]  = {1e30f, 1e30f, 1e30f, 1e30f};   // min over cols of d2
    float colminl[4] = {1e30f, 1e30f, 1e30f, 1e30f};   // min over rows of d2*rconf^2
    #pragma unroll
    for (int ct = 0; ct < 4; ++ct) {
        #pragma unroll
        for (int q = 0; q < 4; ++q) {
            float d2 = fmaf(-2.f, acc[ct][q], pn4[q] + tn4[ct]);
            rowmin[q]   = fminf(rowmin[q], d2);
            colminl[ct] = fminf(colminl[ct], d2 * rc4[q]);
        }
    }
    // row-min across the 16 col-lanes (bits 0..3)
    #pragma unroll
    for (int m = 1; m <= 8; m <<= 1) {
        #pragma unroll
        for (int q = 0; q < 4; ++q)
            rowmin[q] = fminf(rowmin[q], __shfl_xor(rowmin[q], m, 64));
    }
    float s = 0.f;
    if (lr == 0) {
        #pragma unroll
        for (int q = 0; q < 4; ++q) s = fmaf(cf4[q], sqrtf(fmaxf(rowmin[q], 0.f)), s);
    }
    s += __shfl_xor(s, 16, 64);
    s += __shfl_xor(s, 32, 64);
    if (l == 0) t1part[w] = s;
    // col-min across the 4 row-groups (bits 4..5)
    #pragma unroll
    for (int m = 16; m <= 32; m <<= 1) {
        #pragma unroll
        for (int ct = 0; ct < 4; ++ct)
            colminl[ct] = fminf(colminl[ct], __shfl_xor(colminl[ct], m, 64));
    }
    if (l < 16) {
        #pragma unroll
        for (int ct = 0; ct < 4; ++ct) colpart[w][ct * 16 + l] = colminl[ct];
    }
    __syncthreads();

    // ---- final reduce (wave 0) ----
    if (tid < 64) {
        float m0 = fminf(fminf(colpart[0][tid], colpart[1][tid]),
                         fminf(colpart[2][tid], colpart[3][tid]));
        float v = sqrtf(fmaxf(m0, 0.f));
        if (tid < 4) v += t1part[tid];
        #pragma unroll
        for (int m = 1; m <= 32; m <<= 1) v += __shfl_xor(v, m, 64);
        if (tid == 0) out[bid] = v;
    }
}

extern "C" void kernel_launch(void* const* d_in, const int* in_sizes, int n_in,
                              void* d_out, int out_size, void* d_ws, size_t ws_size,
                              hipStream_t stream) {
    const float* inputs  = (const float*)d_in[0];
    const float* targets = (const float*)d_in[1];
    float* out = (float*)d_out;
    hipLaunchKernelGGL(chamfer_mfma, dim3(1024), dim3(256), 0, stream,
                       inputs, targets, out);
}